// Round 2
// 408.217 us; speedup vs baseline: 1.1130x; 1.1130x over previous
//
#include <hip/hip_runtime.h>
#include <hip/hip_bf16.h>
#include <math.h>

// SelfAttentionLayer: B=8,S=2048,D=1024 (fp32 interface).
// R6b: resubmit of R6 (previous round was an infra container failure, no
//   verdict). gemm_f8 LDS de-conflict vs R5:
//   R5 had 64B LDS rows -> bank = (16r+4pos)%32 spans only 16 of 32 banks
//   (XOR over row&3 can't reach the other half): 1.26e7 SQ_LDS_BANK_CONFLICT
//   cycles/dispatch ~= 2x ds_read cost; kernel was LDS-throughput-bound
//   (LDS ~41us vs MFMA ~15us of a 76us dispatch).
//   Fix: BK 64->128 fp8 bytes = 128B LDS rows, chunk swizzle pos = c ^ (row&7)
//   over all 8 bank-quads -> conflict-free ds_read_b128 (4 lanes/quad).
//   2 stages x 32KB = 64KB LDS (2 blocks/CU), depth-1 prefetch, vmcnt(0)+
//   barrier per iter (half the barriers of R5). Staging: linear LDS dest +
//   inverse-swizzled per-lane global source (same XOR involution as reads);
//   global access stays coalesced (8 rows x 128B contiguous per wave).
// Numerics identical to R5: MX-fp8 e4m3 unit scales, P x256, AO x16,
//   residual+LN fp32, preLN bf16. Kept: XCD chunk swizzle.

typedef __bf16 bf16;
typedef unsigned char u8;
typedef __attribute__((ext_vector_type(8))) __bf16 bf16x8;
typedef __attribute__((ext_vector_type(4))) __bf16 bf16x4;
typedef __attribute__((ext_vector_type(8))) int i32x8;
typedef __attribute__((ext_vector_type(16))) float f32x16;

__device__ __forceinline__ void async16(const u8* g, u8* l) {
    __builtin_amdgcn_global_load_lds(
        (const __attribute__((address_space(1))) void*)g,
        (__attribute__((address_space(3))) void*)l, 16, 0, 0);
}

// s_waitcnt imm: bits[3:0] vmcnt, [6:4] expcnt, [11:8] lgkmcnt
#define WAITCNT_VM(n) __builtin_amdgcn_s_waitcnt((15 << 8) | (7 << 4) | (n))

__device__ __forceinline__ u8 to_fp8(float v) {
    return (u8)(__builtin_amdgcn_cvt_pk_fp8_f32(v, v, 0, 0) & 0xFF);
}

__global__ __launch_bounds__(256) void cast_f32_fp8(
    const float* __restrict__ in, u8* __restrict__ out, int n)
{
    int i = (blockIdx.x * 256 + threadIdx.x) * 8;
    if (i >= n) return;
    float4 a = *(const float4*)(in + i);
    float4 b = *(const float4*)(in + i + 4);
    int lo = __builtin_amdgcn_cvt_pk_fp8_f32(a.x, a.y, 0, 0);
    lo = __builtin_amdgcn_cvt_pk_fp8_f32(a.z, a.w, lo, 1);
    int hi = __builtin_amdgcn_cvt_pk_fp8_f32(b.x, b.y, 0, 0);
    hi = __builtin_amdgcn_cvt_pk_fp8_f32(b.z, b.w, hi, 1);
    int2 o = { lo, hi };
    *(int2*)(out + i) = o;
}

// C[m,n] = scale * sum_k A[m,k]*B[n,k] (+bias); A:[M,K] lda, B:[N,K] ldb, fp8.
// bias_mode: 0 none, 1 bias[n], 2 bias[m]. c_mode: 0 bf16 out, 1 fp8 out.
// grid (N/128, M/128, batch), 256 thr = 4 waves, wave=64x64 (2x2 of 32x32x64).
// K must be a multiple of 128.
__global__ __launch_bounds__(256) void gemm_f8(
    const u8* __restrict__ A, long lda, long sA,
    const u8* __restrict__ B, long ldb, long sB,
    void* __restrict__ Cv, long ldc, long sC,
    const float* __restrict__ bias, int bias_mode,
    float scale, int c_mode, int K)
{
    __shared__ u8 lds[2][32768];   // 2 stages x (A 16KB | B 16KB), 128B rows

    // XCD chunk swizzle: flat%8 is the XCD round-robin -> give each XCD a
    // contiguous flat range for L2 tile reuse.
    const int gx = gridDim.x, gy = gridDim.y;
    const int slice = gx * gy;
    const int total = slice * gridDim.z;
    int flat = ((int)blockIdx.z * gy + (int)blockIdx.y) * gx + (int)blockIdx.x;
    if ((total & 7) == 0)
        flat = (flat & 7) * (total >> 3) + (flat >> 3);
    const int bz = flat / slice;
    const int rem = flat - bz * slice;
    const int by = rem / gx;
    const int bx = rem - by * gx;

    const int tid = threadIdx.x;
    const long tM = (long)by * 128;
    const long tN = (long)bx * 128;
    A += (long)bz * sA;
    B += (long)bz * sB;

    // staging: LDS slot s = row*8 + pos holds global chunk c = pos ^ (row&7)
    // (involution). Thread tid covers rows j*32 + (tid>>3), chunk
    // (tid&7)^((tid>>3)&7), LDS dest j*4096 + tid*16 (lane-linear, required
    // by global_load_lds). Per wave: 8 rows x 128B contiguous -> coalesced.
    const int srow = tid >> 3;                    // 0..31
    const int schunk = (tid & 7) ^ (srow & 7);
    const u8* gAs = A + (tM + srow) * lda + schunk * 16;
    const u8* gBs = B + (tN + srow) * ldb + schunk * 16;
    const int ldst = tid * 16;

    const int w = tid >> 6, lane = tid & 63;
    const int wm = (w & 1) * 64, wn = (w >> 1) * 64;
    const int r32 = lane & 31, kh = lane >> 5;   // kh: which 32-byte K-half

    f32x16 acc[2][2] = {};

    const int iters = K >> 7;

    // prologue: stage 0
    {
        u8* p = lds[0];
        async16(gAs,            p + ldst);
        async16(gAs + 32 * lda, p + 4096 + ldst);
        async16(gAs + 64 * lda, p + 8192 + ldst);
        async16(gAs + 96 * lda, p + 12288 + ldst);
        async16(gBs,            p + 16384 + ldst);
        async16(gBs + 32 * ldb, p + 20480 + ldst);
        async16(gBs + 64 * ldb, p + 24576 + ldst);
        async16(gBs + 96 * ldb, p + 28672 + ldst);
    }

    // fragment LDS offsets. Row byte base = row*128 (+16384 for B); chunk c
    // at byte ((c ^ (row&7))<<4). wm,wn are multiples of 32 so row&7 == r32&7
    // for all four fragment rows. MFMA kq (k 0..63 / 64..127) + kh (32B half)
    // -> chunks {kq*4+kh*2, +1}.
    const int xr = r32 & 7;
    const int rA0 = (wm + r32) * 128;
    const int rA1 = rA0 + 32 * 128;
    const int rB0 = 16384 + (wn + r32) * 128;
    const int rB1 = rB0 + 32 * 128;
    const int c00 = (((kh << 1) + 0) ^ xr) << 4;       // kq=0, chunk 0
    const int c01 = (((kh << 1) + 1) ^ xr) << 4;       // kq=0, chunk 1
    const int c10 = ((4 + (kh << 1) + 0) ^ xr) << 4;   // kq=1, chunk 0
    const int c11 = ((4 + (kh << 1) + 1) ^ xr) << 4;   // kq=1, chunk 1

    int cur = 0;
    for (int it = 0; it < iters; ++it) {
        // all 8 outstanding loads are stage[cur]'s; per-wave wait + barrier
        // makes every wave's loads visible to all.
        WAITCNT_VM(0);
        __builtin_amdgcn_s_barrier();

        if (it + 1 < iters) {
            u8* p = lds[cur ^ 1];
            const long ko = (long)(it + 1) << 7;
            async16(gAs + ko,            p + ldst);
            async16(gAs + 32 * lda + ko, p + 4096 + ldst);
            async16(gAs + 64 * lda + ko, p + 8192 + ldst);
            async16(gAs + 96 * lda + ko, p + 12288 + ldst);
            async16(gBs + ko,            p + 16384 + ldst);
            async16(gBs + 32 * ldb + ko, p + 20480 + ldst);
            async16(gBs + 64 * ldb + ko, p + 24576 + ldst);
            async16(gBs + 96 * ldb + ko, p + 28672 + ldst);
        }

        const u8* curb = lds[cur];
        union F { i32x8 v; int4 q[2]; };
        F a0k0, a1k0, b0k0, b1k0, a0k1, a1k1, b0k1, b1k1;
        a0k0.q[0] = *(const int4*)&curb[rA0 + c00];
        a0k0.q[1] = *(const int4*)&curb[rA0 + c01];
        a1k0.q[0] = *(const int4*)&curb[rA1 + c00];
        a1k0.q[1] = *(const int4*)&curb[rA1 + c01];
        b0k0.q[0] = *(const int4*)&curb[rB0 + c00];
        b0k0.q[1] = *(const int4*)&curb[rB0 + c01];
        b1k0.q[0] = *(const int4*)&curb[rB1 + c00];
        b1k0.q[1] = *(const int4*)&curb[rB1 + c01];
        a0k1.q[0] = *(const int4*)&curb[rA0 + c10];
        a0k1.q[1] = *(const int4*)&curb[rA0 + c11];
        a1k1.q[0] = *(const int4*)&curb[rA1 + c10];
        a1k1.q[1] = *(const int4*)&curb[rA1 + c11];
        b0k1.q[0] = *(const int4*)&curb[rB0 + c10];
        b0k1.q[1] = *(const int4*)&curb[rB0 + c11];
        b1k1.q[0] = *(const int4*)&curb[rB1 + c10];
        b1k1.q[1] = *(const int4*)&curb[rB1 + c11];

        // fmt 0 = OCP fp8 e4m3; scales 0x7F (=2^0) in every byte, opsel 0
        acc[0][0] = __builtin_amdgcn_mfma_scale_f32_32x32x64_f8f6f4(
            a0k0.v, b0k0.v, acc[0][0], 0, 0, 0, 0x7F7F7F7F, 0, 0x7F7F7F7F);
        acc[0][1] = __builtin_amdgcn_mfma_scale_f32_32x32x64_f8f6f4(
            a0k0.v, b1k0.v, acc[0][1], 0, 0, 0, 0x7F7F7F7F, 0, 0x7F7F7F7F);
        acc[1][0] = __builtin_amdgcn_mfma_scale_f32_32x32x64_f8f6f4(
            a1k0.v, b0k0.v, acc[1][0], 0, 0, 0, 0x7F7F7F7F, 0, 0x7F7F7F7F);
        acc[1][1] = __builtin_amdgcn_mfma_scale_f32_32x32x64_f8f6f4(
            a1k0.v, b1k0.v, acc[1][1], 0, 0, 0, 0x7F7F7F7F, 0, 0x7F7F7F7F);
        acc[0][0] = __builtin_amdgcn_mfma_scale_f32_32x32x64_f8f6f4(
            a0k1.v, b0k1.v, acc[0][0], 0, 0, 0, 0x7F7F7F7F, 0, 0x7F7F7F7F);
        acc[0][1] = __builtin_amdgcn_mfma_scale_f32_32x32x64_f8f6f4(
            a0k1.v, b1k1.v, acc[0][1], 0, 0, 0, 0x7F7F7F7F, 0, 0x7F7F7F7F);
        acc[1][0] = __builtin_amdgcn_mfma_scale_f32_32x32x64_f8f6f4(
            a1k1.v, b0k1.v, acc[1][0], 0, 0, 0, 0x7F7F7F7F, 0, 0x7F7F7F7F);
        acc[1][1] = __builtin_amdgcn_mfma_scale_f32_32x32x64_f8f6f4(
            a1k1.v, b1k1.v, acc[1][1], 0, 0, 0, 0x7F7F7F7F, 0, 0x7F7F7F7F);

        cur ^= 1;
    }

    // epilogue: 32x32 C/D layout col=lane&31, row=(reg&3)+8*(reg>>2)+4*kh
    // [m74/m101; dtype-independent m121-128]
#pragma unroll
    for (int i = 0; i < 2; i++) {
#pragma unroll
        for (int j = 0; j < 2; j++) {
            const long gn = tN + wn + j * 32 + r32;
            const float bn = (bias_mode == 1) ? bias[gn] : 0.0f;
#pragma unroll
            for (int reg = 0; reg < 16; reg++) {
                const int rowf = (reg & 3) + 8 * (reg >> 2) + 4 * kh;
                const long gm = tM + wm + i * 32 + rowf;
                float v = acc[i][j][reg] * scale + bn;
                if (bias_mode == 2) v += bias[gm];
                if (c_mode == 0)
                    ((bf16*)Cv + (long)bz * sC)[gm * ldc + gn] = (bf16)v;
                else
                    ((u8*)Cv + (long)bz * sC)[gm * ldc + gn] = to_fp8(v);
            }
        }
    }
}

// softmax over rows of 2048 bf16 scores -> fp8 P scaled x256
__global__ __launch_bounds__(256) void softmax_f8(
    const bf16* __restrict__ S, u8* __restrict__ P)
{
    const long row = blockIdx.x;
    const bf16* p = S + row * 2048;
    const int t = threadIdx.x;

    bf16x8 v = *(const bf16x8*)(p + t * 8);
    float f[8];
    float m = -3.0e38f;
#pragma unroll
    for (int i = 0; i < 8; i++) { f[i] = (float)v[i]; m = fmaxf(m, f[i]); }
    for (int o = 32; o; o >>= 1) m = fmaxf(m, __shfl_down(m, o));

    __shared__ float sm[4], ssum[4];
    if ((t & 63) == 0) sm[t >> 6] = m;
    __syncthreads();
    m = fmaxf(fmaxf(sm[0], sm[1]), fmaxf(sm[2], sm[3]));

    float s = 0.0f;
#pragma unroll
    for (int i = 0; i < 8; i++) { f[i] = __expf(f[i] - m); s += f[i]; }
    for (int o = 32; o; o >>= 1) s += __shfl_down(s, o);
    if ((t & 63) == 0) ssum[t >> 6] = s;
    __syncthreads();
    s = ssum[0] + ssum[1] + ssum[2] + ssum[3];

    const float c = 256.0f / s;   // x256: keep P out of fp8 subnormal range
    int lo = __builtin_amdgcn_cvt_pk_fp8_f32(f[0] * c, f[1] * c, 0, 0);
    lo = __builtin_amdgcn_cvt_pk_fp8_f32(f[2] * c, f[3] * c, lo, 1);
    int hi = __builtin_amdgcn_cvt_pk_fp8_f32(f[4] * c, f[5] * c, 0, 0);
    hi = __builtin_amdgcn_cvt_pk_fp8_f32(f[6] * c, f[7] * c, hi, 1);
    int2 o = { lo, hi };
    *(int2*)(P + row * 2048 + t * 8) = o;
}

// out = LN(pre + x) * gamma + beta; pre bf16, x fp32; rows of 1024
__global__ __launch_bounds__(256) void ln_res(
    const bf16* __restrict__ pre, const float* __restrict__ x,
    const float* __restrict__ gamma, const float* __restrict__ beta,
    float* __restrict__ out)
{
    const long row = blockIdx.x;
    const int t = threadIdx.x;
    const long base = row * 1024 + t * 4;

    bf16x4 a = *(const bf16x4*)(pre + base);
    float4 b = *(const float4*)(x + base);
    float v0 = (float)a[0] + b.x, v1 = (float)a[1] + b.y;
    float v2 = (float)a[2] + b.z, v3 = (float)a[3] + b.w;

    float s = v0 + v1 + v2 + v3;
    float q = v0 * v0 + v1 * v1 + v2 * v2 + v3 * v3;
    for (int o = 32; o; o >>= 1) { s += __shfl_down(s, o); q += __shfl_down(q, o); }

    __shared__ float ls[4], lq[4];
    if ((t & 63) == 0) { ls[t >> 6] = s; lq[t >> 6] = q; }
    __syncthreads();
    s = ls[0] + ls[1] + ls[2] + ls[3];
    q = lq[0] + lq[1] + lq[2] + lq[3];

    const float mean = s * (1.0f / 1024.0f);
    const float var = q * (1.0f / 1024.0f) - mean * mean;
    const float rstd = rsqrtf(var + 1e-5f);

    const int c = t * 4;
    float4 g = *(const float4*)(gamma + c);
    float4 be = *(const float4*)(beta + c);
    float4 o;
    o.x = (v0 - mean) * rstd * g.x + be.x;
    o.y = (v1 - mean) * rstd * g.y + be.y;
    o.z = (v2 - mean) * rstd * g.z + be.z;
    o.w = (v3 - mean) * rstd * g.w + be.w;
    *(float4*)(out + base) = o;
}

extern "C" void kernel_launch(void* const* d_in, const int* in_sizes, int n_in,
                              void* d_out, int out_size, void* d_ws, size_t ws_size,
                              hipStream_t stream)
{
    const float* x     = (const float*)d_in[0];
    const float* Wq    = (const float*)d_in[1];
    const float* bq    = (const float*)d_in[2];
    const float* Wk    = (const float*)d_in[3];
    const float* bk    = (const float*)d_in[4];
    const float* Wv    = (const float*)d_in[5];
    const float* bv    = (const float*)d_in[6];
    const float* Wo    = (const float*)d_in[7];
    const float* bo    = (const float*)d_in[8];
    const float* gamma = (const float*)d_in[9];
    const float* beta  = (const float*)d_in[10];
    float* out = (float*)d_out;

    char* ws = (char*)d_ws;
    u8* x8  = (u8*)(ws + (size_t)0);          // 16 MB [16384,1024]
    u8* Q8  = (u8*)(ws + (size_t)16777216);   // 16 MB (reused as AO8)
    u8* K8  = (u8*)(ws + (size_t)33554432);   // 16 MB
    u8* VT8 = (u8*)(ws + (size_t)50331648);   // 16 MB [1024,16384]
    u8* P8  = (u8*)(ws + (size_t)67108864);   // 32 MB [8,2048,2048]
    bf16* Sb = (bf16*)(ws + (size_t)104857600); // 64 MB scores; preLN reuse
    u8* Wq8 = (u8*)(ws + (size_t)176160768);
    u8* Wk8 = Wq8 + 1048576;
    u8* Wv8 = Wk8 + 1048576;
    u8* Wo8 = Wv8 + 1048576;

    // casts
    cast_f32_fp8<<<8192, 256, 0, stream>>>(x, x8, 16777216);
    cast_f32_fp8<<<512, 256, 0, stream>>>(Wq, Wq8, 1048576);
    cast_f32_fp8<<<512, 256, 0, stream>>>(Wk, Wk8, 1048576);
    cast_f32_fp8<<<512, 256, 0, stream>>>(Wv, Wv8, 1048576);
    cast_f32_fp8<<<512, 256, 0, stream>>>(Wo, Wo8, 1048576);

    // Q8 = x8@Wq8^T + bq  (fp8 out)
    gemm_f8<<<dim3(8, 128, 1), 256, 0, stream>>>(
        x8, 1024, 0, Wq8, 1024, 0, (void*)Q8, 1024, 0, bq, 1, 1.0f, 1, 1024);
    // K8
    gemm_f8<<<dim3(8, 128, 1), 256, 0, stream>>>(
        x8, 1024, 0, Wk8, 1024, 0, (void*)K8, 1024, 0, bk, 1, 1.0f, 1, 1024);
    // VT8 = Wv8@x8^T + bv(row)  [1024,16384] fp8
    gemm_f8<<<dim3(128, 8, 1), 256, 0, stream>>>(
        Wv8, 1024, 0, x8, 1024, 0, (void*)VT8, 16384, 0, bv, 2, 1.0f, 1, 1024);
    // scores (bf16) = Q8@K8^T / 32, per batch
    gemm_f8<<<dim3(16, 16, 8), 256, 0, stream>>>(
        Q8, 1024, 2097152, K8, 1024, 2097152, (void*)Sb, 2048, 4194304,
        nullptr, 0, 0.03125f, 0, 1024);
    // P8 = softmax(scores) * 256  (fp8)
    softmax_f8<<<16384, 256, 0, stream>>>(Sb, P8);
    // AO8 = (P8@VT8^T) * 16/256  -> stored AO = 16*AO_true (into Q8)
    gemm_f8<<<dim3(8, 16, 8), 256, 0, stream>>>(
        P8, 2048, 4194304, VT8, 16384, 2048, (void*)Q8, 1024, 2097152,
        nullptr, 0, 0.0625f, 1, 2048);
    // preLN (bf16, into Sb) = AO8@Wo8^T * (1/16) + bo
    gemm_f8<<<dim3(8, 128, 1), 256, 0, stream>>>(
        Q8, 1024, 0, Wo8, 1024, 0, (void*)Sb, 1024, 0, bo, 1, 0.0625f, 0, 1024);
    // out = LN(pre + x)
    ln_res<<<16384, 256, 0, stream>>>((const bf16*)Sb, x, gamma, beta, out);
}